// Round 2
// baseline (318.170 us; speedup 1.0000x reference)
//
#include <hip/hip_runtime.h>
#include <hip/hip_bf16.h>

// AttentionGrouping: B=4096 graphs, N=32 nodes, D=128, H=2 heads.
// Inputs fp32 (per reference dtypes), outputs fp32: out=[B*N,128] then
// weight=[B*N,32,2], concatenated flat in d_out.
//
// Internally bf16 MFMA (fp32 accumulate): input-rounding error ~1e-2 abs,
// well under the harness's printed 6.25e-2 threshold.
//
// Kernel 1: pack WQ/WK/WV (fp32 [128][256] row-major) into bf16 MFMA
//           B-fragment order so the fused kernel's B loads are coalesced.
// Kernel 2: one block per graph (4096 blocks x 256 threads):
//   0) x[32][128] fp32 -> bf16 LDS (padded stride 136)
//   1) q,k,v = x@W via mfma_f32_16x16x32_bf16 (A-frags register-cached);
//      q,k -> LDS bf16 [32][264]; v -> LDS transposed [256][40]
//   2) scores S_h = Q_h K_h^T / 16 -> LDS fp32 [2][32][33]
//   3) sparsemax over j (sort-free rank/cumsum scan, 32 lanes per row);
//      w -> LDS bf16 + fp32 global weight store
//   4) out = 0.5*(W_0 V_0 + W_1 V_1) via chained MFMA, fp32 store
// LDS aliasing: scores overlap x (dead), w overlaps q (dead). 62976 B/WG.

#define NG 4096
#define NN 32
#define DD 128

typedef short bf16x8 __attribute__((ext_vector_type(8)));
typedef float f32x4 __attribute__((ext_vector_type(4)));

__device__ inline short f2bf(float f) {
    __hip_bfloat16 h = __float2bfloat16(f);
    return __builtin_bit_cast(short, h);
}

// packed[((p*16+nt)*4+s)*512 + lane*8 + j] = bf16(W_p[(s*32+(lane>>4)*8+j)*256 + nt*16+(lane&15)])
__global__ void pack_w_kernel(const float* __restrict__ WK, const float* __restrict__ WV,
                              const float* __restrict__ WQ, short* __restrict__ packed) {
    int idx = blockIdx.x * 256 + threadIdx.x;
    if (idx >= 3 * 16 * 4 * 64 * 8) return;
    int j    = idx & 7;
    int lane = (idx >> 3) & 63;
    int s    = (idx >> 9) & 3;
    int t    = (idx >> 11) & 15;
    int p    = idx >> 15;                 // 0=Q 1=K 2=V
    int krow = s * 32 + (lane >> 4) * 8 + j;
    int col  = t * 16 + (lane & 15);
    const float* W = (p == 0) ? WQ : (p == 1) ? WK : WV;
    packed[idx] = f2bf(W[krow * 256 + col]);
}

__global__ __launch_bounds__(256, 2)
void fused_attn_kernel(const float* __restrict__ x, const short* __restrict__ packed,
                       float* __restrict__ out, float* __restrict__ wgt) {
    __shared__ char __align__(16) smem[62976];
    short* x_s  = (short*)smem;               // [32][136] bf16, 8704 B
    float* s_s  = (float*)smem;               // [2][32][33] f32, 8448 B (aliases x)
    short* q_s  = (short*)(smem + 8704);      // [32][264] bf16, 16896 B
    short* w_s  = (short*)(smem + 8704);      // [2][32][40] bf16, 5120 B (aliases q)
    short* k_s  = (short*)(smem + 25600);     // [32][264] bf16, 16896 B
    short* vT_s = (short*)(smem + 42496);     // [256][40] bf16, 20480 B

    int b    = blockIdx.x;
    int tid  = threadIdx.x;
    int lane = tid & 63;
    int wave = tid >> 6;
    int lrow = lane & 15;
    int quad = lane >> 4;

    // ---- phase 0: load x fp32, convert to bf16 LDS ----
    const float* xg = x + b * (NN * DD);
    {
        int e = tid * 16;                     // 256 threads x 16 = 4096
        int row = e >> 7, col = e & 127;      // col in {0,16,...,112}: no row straddle
        bf16x8 v0, v1;
        #pragma unroll
        for (int t = 0; t < 8; ++t) {
            v0[t] = f2bf(xg[e + t]);
            v1[t] = f2bf(xg[e + 8 + t]);
        }
        *(bf16x8*)&x_s[row * 136 + col]     = v0;
        *(bf16x8*)&x_s[row * 136 + col + 8] = v1;
    }
    __syncthreads();

    // ---- phase 1: projections ----
    bf16x8 afrag[2][4];
    #pragma unroll
    for (int mt = 0; mt < 2; ++mt)
        #pragma unroll
        for (int s = 0; s < 4; ++s)
            afrag[mt][s] = *(const bf16x8*)&x_s[(mt * 16 + lrow) * 136 + s * 32 + quad * 8];

    #pragma unroll
    for (int ii = 0; ii < 12; ++ii) {
        int pi = wave + ii * 4;               // 0..47
        int p  = pi >> 4;
        int nt = pi & 15;
        const short* pb = packed + pi * 4 * 512 + lane * 8;
        bf16x8 bfrag[4];
        #pragma unroll
        for (int s = 0; s < 4; ++s) bfrag[s] = *(const bf16x8*)&pb[s * 512];
        f32x4 acc0 = {0.f, 0.f, 0.f, 0.f}, acc1 = {0.f, 0.f, 0.f, 0.f};
        #pragma unroll
        for (int s = 0; s < 4; ++s) {
            acc0 = __builtin_amdgcn_mfma_f32_16x16x32_bf16(afrag[0][s], bfrag[s], acc0, 0, 0, 0);
            acc1 = __builtin_amdgcn_mfma_f32_16x16x32_bf16(afrag[1][s], bfrag[s], acc1, 0, 0, 0);
        }
        int c = nt * 16 + lrow;
        #pragma unroll
        for (int r = 0; r < 4; ++r) {
            int i0 = quad * 4 + r;            // D row = (lane>>4)*4 + reg
            short v0 = f2bf(acc0[r]), v1 = f2bf(acc1[r]);
            if (p == 0)      { q_s[i0 * 264 + c] = v0; q_s[(i0 + 16) * 264 + c] = v1; }
            else if (p == 1) { k_s[i0 * 264 + c] = v0; k_s[(i0 + 16) * 264 + c] = v1; }
            else             { vT_s[c * 40 + i0] = v0; vT_s[c * 40 + i0 + 16]  = v1; }
        }
    }
    __syncthreads();

    // ---- phase 2: scores S_h = Q_h K_h^T / 16 ----
    #pragma unroll
    for (int tt = 0; tt < 2; ++tt) {
        int ti = wave + tt * 4;               // 0..7 = h(2) x it2(2) x jt(2)
        int h  = ti >> 2;
        int it2 = (ti >> 1) & 1;
        int jt = ti & 1;
        f32x4 acc = {0.f, 0.f, 0.f, 0.f};
        #pragma unroll
        for (int s = 0; s < 4; ++s) {
            bf16x8 aq = *(const bf16x8*)&q_s[(it2 * 16 + lrow) * 264 + h * 128 + s * 32 + quad * 8];
            bf16x8 bk = *(const bf16x8*)&k_s[(jt * 16 + lrow) * 264 + h * 128 + s * 32 + quad * 8];
            acc = __builtin_amdgcn_mfma_f32_16x16x32_bf16(aq, bk, acc, 0, 0, 0);
        }
        #pragma unroll
        for (int r = 0; r < 4; ++r) {
            int i  = it2 * 16 + quad * 4 + r;
            int jj = jt * 16 + lrow;
            s_s[(h * 32 + i) * 33 + jj] = acc[r] * 0.0625f;   // 1/sqrt(128*2)
        }
    }
    __syncthreads();

    // ---- phase 3: sparsemax over j, 32 lanes per (h,i) row ----
    {
        int j = tid & 31;
        int rgrp = tid >> 5;                  // 0..7
        for (int rr = 0; rr < 8; ++rr) {
            int row = rgrp + rr * 8;          // 0..63
            int h = row >> 5, i = row & 31;
            const float* zrow = &s_s[(h * 32 + i) * 33];
            float zj = zrow[j];
            int cnt = 0; float sum = 0.f;
            #pragma unroll
            for (int l = 0; l < 32; ++l) {
                float zl = zrow[l];
                bool gt = (zl > zj) || (zl == zj && l < j);   // stable rank
                cnt += gt ? 1 : 0;
                sum += gt ? zl : 0.f;
            }
            float rk  = (float)(cnt + 1);
            float cum = sum + zj;
            bool flag = (1.f + rk * zj) > cum;
            int key   = flag ? (cnt + 1) : 0;
            float cs  = flag ? cum : 0.f;
            #pragma unroll
            for (int m = 16; m >= 1; m >>= 1) {
                int   ok = __shfl_xor(key, m, 32);
                float oc = __shfl_xor(cs, m, 32);
                if (ok > key) { key = ok; cs = oc; }
            }
            float tau = (cs - 1.f) / (float)key;   // key >= 1 (rank-1 always in support)
            float w = zj - tau; w = w < 0.f ? 0.f : w;
            w_s[(h * 32 + i) * 40 + j] = f2bf(w);
            wgt[((b * 32 + i) * 32 + j) * 2 + h] = w;
        }
    }
    __syncthreads();

    // ---- phase 4: out = 0.5 * (W_0 V_0 + W_1 V_1) ----
    #pragma unroll
    for (int tt = 0; tt < 4; ++tt) {
        int ti = wave + tt * 4;               // 0..15 = it2(2) x dt(8)
        int it2 = ti >> 3;
        int dt  = ti & 7;
        f32x4 acc = {0.f, 0.f, 0.f, 0.f};
        #pragma unroll
        for (int h = 0; h < 2; ++h) {
            bf16x8 aw = *(const bf16x8*)&w_s[(h * 32 + it2 * 16 + lrow) * 40 + quad * 8];
            bf16x8 bv = *(const bf16x8*)&vT_s[(h * 128 + dt * 16 + lrow) * 40 + quad * 8];
            acc = __builtin_amdgcn_mfma_f32_16x16x32_bf16(aw, bv, acc, 0, 0, 0);
        }
        #pragma unroll
        for (int r = 0; r < 4; ++r) {
            int i = it2 * 16 + quad * 4 + r;
            int d = dt * 16 + lrow;
            out[(b * 32 + i) * 128 + d] = acc[r] * 0.5f;
        }
    }
}

extern "C" void kernel_launch(void* const* d_in, const int* in_sizes, int n_in,
                              void* d_out, int out_size, void* d_ws, size_t ws_size,
                              hipStream_t stream) {
    const float* x  = (const float*)d_in[0];  // node_feature [4096,32,128] fp32
    const float* WK = (const float*)d_in[1];  // [128,256] fp32
    const float* WV = (const float*)d_in[2];
    const float* WQ = (const float*)d_in[3];
    float* out = (float*)d_out;               // [131072,128] fp32
    float* wgt = out + NG * NN * DD;          // [131072,32,2] fp32
    short* packed = (short*)d_ws;             // 98304 bf16 = 196608 B

    hipLaunchKernelGGL(pack_w_kernel, dim3(384), dim3(256), 0, stream, WK, WV, WQ, packed);
    hipLaunchKernelGGL(fused_attn_kernel, dim3(NG), dim3(256), 0, stream, x, packed, out, wgt);
}

// Round 3
// 260.126 us; speedup vs baseline: 1.2231x; 1.2231x over previous
//
#include <hip/hip_runtime.h>
#include <hip/hip_bf16.h>

// AttentionGrouping: B=4096 graphs, N=32 nodes, D=128, H=2 heads.
// Inputs fp32, outputs fp32: out=[B*N,128] then weight=[B*N,32,2] in d_out.
//
// R3 restructure: x global->registers (no LDS), Q/K projected transposed /
// V normal so all proj LDS stores are packed ds_write_b64; sparsemax via
// 32-lane bitonic sort + shuffle scan (1 vector LDS read per row); coalesced
// float2 weight stores. 3 barriers. LDS 63488 B -> 2 blocks/CU.

#define NG 4096

typedef short bf16x8 __attribute__((ext_vector_type(8)));
typedef float f32x4 __attribute__((ext_vector_type(4)));

__device__ inline short f2bf(float f) {
    __hip_bfloat16 h = __float2bfloat16(f);
    return __builtin_bit_cast(short, h);
}
__device__ inline unsigned pack2(float a, float b) {
    return (unsigned)(unsigned short)f2bf(a) | ((unsigned)(unsigned short)f2bf(b) << 16);
}

// packed[((p*16+t)*4+s)*512 + lane*8 + j] = bf16(W_p[s*32+(lane>>4)*8+j][t*16+(lane&15)])
// Serves as B-frag of W (normal proj) AND A-frag of W^T (transposed proj).
__global__ void pack_w_kernel(const float* __restrict__ WK, const float* __restrict__ WV,
                              const float* __restrict__ WQ, short* __restrict__ packed) {
    int idx = blockIdx.x * 256 + threadIdx.x;
    if (idx >= 3 * 16 * 4 * 64 * 8) return;
    int j    = idx & 7;
    int lane = (idx >> 3) & 63;
    int s    = (idx >> 9) & 3;
    int t    = (idx >> 11) & 15;
    int p    = idx >> 15;                 // 0=Q 1=K 2=V
    int krow = s * 32 + (lane >> 4) * 8 + j;
    int col  = t * 16 + (lane & 15);
    const float* W = (p == 0) ? WQ : (p == 1) ? WK : WV;
    packed[idx] = f2bf(W[krow * 256 + col]);
}

__global__ __launch_bounds__(256, 2)
void fused_attn_kernel(const float* __restrict__ x, const short* __restrict__ packed,
                       float* __restrict__ out, float* __restrict__ wgt) {
    __shared__ char __align__(16) smem[63488];
    short* q_s  = (short*)smem;               // [32 node][264 d'] bf16, 16896 B
    short* k_s  = (short*)(smem + 16896);     // [32 node][264 d'] bf16, 16896 B
    short* vT_s = (short*)(smem + 33792);     // [256 d'][40 node] bf16, 20480 B
    float* s_s  = (float*)(smem + 54272);     // [64 row][36 j] f32, 9216 B; w aliases row starts

    int b    = blockIdx.x;
    int tid  = threadIdx.x;
    int lane = tid & 63;
    int wave = tid >> 6;
    int lrow = lane & 15;
    int quad = lane >> 4;

    // ---- x -> register fragments (A-frag for V proj, B-frag for Q/K^T proj) ----
    bf16x8 xf[2][4];                          // [node-tile][k-chunk]
    const float* xg = x + (size_t)b * 4096;
    #pragma unroll
    for (int nt = 0; nt < 2; ++nt)
        #pragma unroll
        for (int s = 0; s < 4; ++s) {
            const float* p0 = &xg[(nt * 16 + lrow) * 128 + s * 32 + quad * 8];
            float4 f0 = *(const float4*)p0;
            float4 f1 = *(const float4*)(p0 + 4);
            bf16x8 v;
            v[0]=f2bf(f0.x); v[1]=f2bf(f0.y); v[2]=f2bf(f0.z); v[3]=f2bf(f0.w);
            v[4]=f2bf(f1.x); v[5]=f2bf(f1.y); v[6]=f2bf(f1.z); v[7]=f2bf(f1.w);
            xf[nt][s] = v;
        }

    // ---- phase 1: projections ----
    // Q,K transposed: C^T[d'][node] = W^T x^T; 4-reg M-dim = consecutive d'
    //   -> packed b64 store into q_s/k_s[node][d'].
    #pragma unroll
    for (int p = 0; p < 2; ++p) {
        short* dst = p ? k_s : q_s;
        #pragma unroll
        for (int t = 0; t < 4; ++t) {
            int mt = wave * 4 + t;            // d'-tile 0..15
            const short* pb = packed + ((p * 16 + mt) * 4) * 512 + lane * 8;
            bf16x8 wf[4];
            #pragma unroll
            for (int s = 0; s < 4; ++s) wf[s] = *(const bf16x8*)&pb[s * 512];
            f32x4 acc[2] = {{0.f,0.f,0.f,0.f},{0.f,0.f,0.f,0.f}};
            #pragma unroll
            for (int nt = 0; nt < 2; ++nt)
                #pragma unroll
                for (int s = 0; s < 4; ++s)
                    acc[nt] = __builtin_amdgcn_mfma_f32_16x16x32_bf16(wf[s], xf[nt][s], acc[nt], 0, 0, 0);
            #pragma unroll
            for (int nt = 0; nt < 2; ++nt) {
                int addr = (nt * 16 + lrow) * 264 + mt * 16 + quad * 4;
                uint2 pk; pk.x = pack2(acc[nt][0], acc[nt][1]); pk.y = pack2(acc[nt][2], acc[nt][3]);
                *(uint2*)&dst[addr] = pk;
            }
        }
    }
    // V normal: C[node][col]; 4-reg M-dim = consecutive node -> b64 into vT[col][node].
    #pragma unroll
    for (int t = 0; t < 4; ++t) {
        int ntv = wave * 4 + t;               // col-tile 0..15
        const short* pb = packed + ((2 * 16 + ntv) * 4) * 512 + lane * 8;
        bf16x8 wf[4];
        #pragma unroll
        for (int s = 0; s < 4; ++s) wf[s] = *(const bf16x8*)&pb[s * 512];
        f32x4 acc[2] = {{0.f,0.f,0.f,0.f},{0.f,0.f,0.f,0.f}};
        #pragma unroll
        for (int mt = 0; mt < 2; ++mt)
            #pragma unroll
            for (int s = 0; s < 4; ++s)
                acc[mt] = __builtin_amdgcn_mfma_f32_16x16x32_bf16(xf[mt][s], wf[s], acc[mt], 0, 0, 0);
        #pragma unroll
        for (int mt = 0; mt < 2; ++mt) {
            int addr = (ntv * 16 + lrow) * 40 + mt * 16 + quad * 4;
            uint2 pk; pk.x = pack2(acc[mt][0], acc[mt][1]); pk.y = pack2(acc[mt][2], acc[mt][3]);
            *(uint2*)&vT_s[addr] = pk;
        }
    }
    __syncthreads();

    // ---- phase 2: S_h = Q_h K_h^T / 16 -> s_s[64][36] ----
    #pragma unroll
    for (int tt = 0; tt < 2; ++tt) {
        int ti = wave * 2 + tt;               // 0..7 = h(2) x it(2) x jt(2)
        int h = ti >> 2, it = (ti >> 1) & 1, jt = ti & 1;
        f32x4 acc = {0.f, 0.f, 0.f, 0.f};
        #pragma unroll
        for (int s = 0; s < 4; ++s) {
            bf16x8 aq = *(const bf16x8*)&q_s[(it * 16 + lrow) * 264 + h * 128 + s * 32 + quad * 8];
            bf16x8 bk = *(const bf16x8*)&k_s[(jt * 16 + lrow) * 264 + h * 128 + s * 32 + quad * 8];
            acc = __builtin_amdgcn_mfma_f32_16x16x32_bf16(aq, bk, acc, 0, 0, 0);
        }
        #pragma unroll
        for (int r = 0; r < 4; ++r)
            s_s[(h * 32 + it * 16 + quad * 4 + r) * 36 + jt * 16 + lrow] = acc[r] * 0.0625f;
    }
    __syncthreads();

    // ---- phase 3: sparsemax; lanes 0-31 h=0, 32-63 h=1; one i per iter ----
    {
        int j = lane & 31;
        int hh = lane >> 5;
        #pragma unroll
        for (int ii = 0; ii < 8; ++ii) {
            int i = wave * 8 + ii;
            int row = hh * 32 + i;
            float zorig = s_s[row * 36 + j];
            float z = zorig;
            // bitonic ascending sort across 32-lane halves
            #pragma unroll
            for (int k = 2; k <= 32; k <<= 1)
                #pragma unroll
                for (int m = k >> 1; m >= 1; m >>= 1) {
                    float p = __shfl_xor(z, m);
                    bool up = ((j & k) == 0);
                    bool lo = ((j & m) == 0);
                    float mn = fminf(z, p), mx = fmaxf(z, p);
                    z = (up == lo) ? mn : mx;
                }
            float zd = __shfl_xor(z, 31);     // descending: lane j = (j+1)-th largest
            float cum = zd;
            #pragma unroll
            for (int d = 1; d <= 16; d <<= 1) {
                float t = __shfl_up(cum, d, 32);
                cum += (j >= d) ? t : 0.f;
            }
            float rank = (float)(j + 1);
            bool flag = (1.f + rank * zd) > cum;
            int fn = __shfl_down((int)flag, 1, 32);
            bool boundary = flag && ((j == 31) ? true : !fn);
            float tc = boundary ? (cum - 1.f) / rank : -3.0e38f;
            #pragma unroll
            for (int m = 1; m <= 16; m <<= 1) tc = fmaxf(tc, __shfl_xor(tc, m));
            float w = fmaxf(zorig - tc, 0.f);
            ((short*)&s_s[row * 36])[j] = f2bf(w);        // w aliases S row start
            float wo = __shfl_xor(w, 32);                 // pair heads
            if (lane < 32) {
                float2 v; v.x = w; v.y = wo;
                *(float2*)&wgt[((size_t)b * 32 + i) * 64 + j * 2] = v;
            }
        }
    }
    __syncthreads();

    // ---- phase 4: out = 0.5*(W_0 V_0 + W_1 V_1) ----
    #pragma unroll
    for (int tt = 0; tt < 4; ++tt) {
        int ti = wave * 4 + tt;               // 0..15 = it(2) x dt(8)
        int it = ti >> 3, dt = ti & 7;
        f32x4 acc = {0.f, 0.f, 0.f, 0.f};
        #pragma unroll
        for (int h = 0; h < 2; ++h) {
            bf16x8 aw = *(const bf16x8*)((short*)&s_s[(h * 32 + it * 16 + lrow) * 36] + quad * 8);
            bf16x8 bv = *(const bf16x8*)&vT_s[(h * 128 + dt * 16 + lrow) * 40 + quad * 8];
            acc = __builtin_amdgcn_mfma_f32_16x16x32_bf16(aw, bv, acc, 0, 0, 0);
        }
        #pragma unroll
        for (int r = 0; r < 4; ++r)
            out[((size_t)b * 32 + it * 16 + quad * 4 + r) * 128 + dt * 16 + lrow] = acc[r] * 0.5f;
    }
}

extern "C" void kernel_launch(void* const* d_in, const int* in_sizes, int n_in,
                              void* d_out, int out_size, void* d_ws, size_t ws_size,
                              hipStream_t stream) {
    const float* x  = (const float*)d_in[0];
    const float* WK = (const float*)d_in[1];
    const float* WV = (const float*)d_in[2];
    const float* WQ = (const float*)d_in[3];
    float* out = (float*)d_out;               // [131072,128] fp32
    float* wgt = out + (size_t)NG * 32 * 128; // [131072,32,2] fp32
    short* packed = (short*)d_ws;             // 98304 bf16

    hipLaunchKernelGGL(pack_w_kernel, dim3(384), dim3(256), 0, stream, WK, WV, WQ, packed);
    hipLaunchKernelGGL(fused_attn_kernel, dim3(NG), dim3(256), 0, stream, x, packed, out, wgt);
}

// Round 4
// 205.814 us; speedup vs baseline: 1.5459x; 1.2639x over previous
//
#include <hip/hip_runtime.h>
#include <hip/hip_bf16.h>

// AttentionGrouping: B=4096 graphs, N=32 nodes, D=128, H=2 heads.
// Inputs fp32, outputs fp32: out=[B*N,128] then weight=[B*N,32,2] in d_out.
//
// R4: S_h = X (WQ_h WK_h^T /16) X^T  — M_h precomputed (pack_m), so Q/K never
// exist. Fused kernel: T = X M (LDS, transposed-store trick for packed b64
// writes), S = T X^T with x register fragments as B operand, sparsemax via
// per-lane full-row scan + tau = max_k (cumsum_k - 1)/k (5-shuffle max only),
// out = W V. LDS 46592 B -> 3 blocks/CU (12 waves).

#define NG 4096

typedef short bf16x8 __attribute__((ext_vector_type(8)));
typedef float f32x4 __attribute__((ext_vector_type(4)));

__device__ inline short f2bf(float f) {
    __hip_bfloat16 h = __float2bfloat16(f);
    return __builtin_bit_cast(short, h);
}
__device__ inline unsigned pack2(float a, float b) {
    return (unsigned)(unsigned short)f2bf(a) | ((unsigned)(unsigned short)f2bf(b) << 16);
}

// packed_m[(mt*4+s)*512 + lane*8 + jj] = bf16( (1/16)*sum_c WQ[a][h*128+c]*WK[bl][h*128+c] )
//   h = mt>>3, a = s*32+(lane>>4)*8+jj (k-dim of T-mfma), bl = (mt&7)*16+(lane&15)
// This is the A-frag of M^T for T^T = M^T X^T.
__global__ void pack_m_kernel(const float* __restrict__ WQ, const float* __restrict__ WK,
                              short* __restrict__ packed_m) {
    int idx  = blockIdx.x * 256 + threadIdx.x;    // 32768 total
    int jj   = idx & 7;
    int lane = (idx >> 3) & 63;
    int s    = (idx >> 9) & 3;
    int mt   = (idx >> 11) & 15;
    int h    = mt >> 3;
    int a    = s * 32 + (lane >> 4) * 8 + jj;
    int bl   = (mt & 7) * 16 + (lane & 15);
    const float4* qa = (const float4*)(WQ + a * 256 + h * 128);
    const float4* kb = (const float4*)(WK + bl * 256 + h * 128);
    float acc = 0.f;
    #pragma unroll 8
    for (int c = 0; c < 32; ++c) {
        float4 q4 = qa[c], k4 = kb[c];
        acc += q4.x * k4.x + q4.y * k4.y + q4.z * k4.z + q4.w * k4.w;
    }
    packed_m[idx] = f2bf(acc * 0.0625f);
}

// packed_v[(t*4+s)*512 + lane*8 + jj] = bf16(WV[s*32+(lane>>4)*8+jj][t*16+(lane&15)])
// B-frag of WV for V = X WV.
__global__ void pack_v_kernel(const float* __restrict__ WV, short* __restrict__ packed_v) {
    int idx  = blockIdx.x * 256 + threadIdx.x;    // 32768 total
    int jj   = idx & 7;
    int lane = (idx >> 3) & 63;
    int s    = (idx >> 9) & 3;
    int t    = (idx >> 11) & 15;
    int krow = s * 32 + (lane >> 4) * 8 + jj;
    int col  = t * 16 + (lane & 15);
    packed_v[idx] = f2bf(WV[krow * 256 + col]);
}

__global__ __launch_bounds__(256, 3)
void fused_attn_kernel(const float* __restrict__ x, const short* __restrict__ pm,
                       const short* __restrict__ pv, float* __restrict__ out,
                       float* __restrict__ wgt) {
    __shared__ char __align__(16) smem[46592];
    short* t_s  = (short*)smem;               // T [32 node][264 d'] bf16, 16896 B
    short* vT_s = (short*)(smem + 16896);     // V^T [256 d'][40 node] bf16, 20480 B
    float* s_s  = (float*)(smem + 37376);     // S [64 row][36 j] f32, 9216 B; w aliases row starts

    int b    = blockIdx.x;
    int tid  = threadIdx.x;
    int lane = tid & 63;
    int wave = tid >> 6;
    int lrow = lane & 15;
    int quad = lane >> 4;

    // ---- x -> register fragments (A-frag for V, B-frag for T/S transposed forms) ----
    bf16x8 xf[2][4];                          // [node-tile][k-chunk]
    const float* xg = x + (size_t)b * 4096;
    #pragma unroll
    for (int nt = 0; nt < 2; ++nt)
        #pragma unroll
        for (int s = 0; s < 4; ++s) {
            const float* p0 = &xg[(nt * 16 + lrow) * 128 + s * 32 + quad * 8];
            float4 f0 = *(const float4*)p0;
            float4 f1 = *(const float4*)(p0 + 4);
            bf16x8 v;
            v[0]=f2bf(f0.x); v[1]=f2bf(f0.y); v[2]=f2bf(f0.z); v[3]=f2bf(f0.w);
            v[4]=f2bf(f1.x); v[5]=f2bf(f1.y); v[6]=f2bf(f1.z); v[7]=f2bf(f1.w);
            xf[nt][s] = v;
        }

    // ---- phase 1a: T^T = M^T X^T -> t_s[node][d'] via packed b64 stores ----
    #pragma unroll
    for (int t = 0; t < 4; ++t) {
        int mt = wave * 4 + t;                // d'-tile 0..15 (head = mt>>3)
        const short* pb = pm + (mt * 4) * 512 + lane * 8;
        bf16x8 wf[4];
        #pragma unroll
        for (int s = 0; s < 4; ++s) wf[s] = *(const bf16x8*)&pb[s * 512];
        f32x4 acc[2] = {{0.f,0.f,0.f,0.f},{0.f,0.f,0.f,0.f}};
        #pragma unroll
        for (int nt = 0; nt < 2; ++nt)
            #pragma unroll
            for (int s = 0; s < 4; ++s)
                acc[nt] = __builtin_amdgcn_mfma_f32_16x16x32_bf16(wf[s], xf[nt][s], acc[nt], 0, 0, 0);
        #pragma unroll
        for (int nt = 0; nt < 2; ++nt) {
            int addr = (nt * 16 + lrow) * 264 + mt * 16 + quad * 4;
            uint2 pk; pk.x = pack2(acc[nt][0], acc[nt][1]); pk.y = pack2(acc[nt][2], acc[nt][3]);
            *(uint2*)&t_s[addr] = pk;
        }
    }
    // ---- phase 1b: V = X WV -> vT_s[d'][node] via packed b64 stores ----
    #pragma unroll
    for (int t = 0; t < 4; ++t) {
        int ntv = wave * 4 + t;               // col-tile 0..15
        const short* pb = pv + (ntv * 4) * 512 + lane * 8;
        bf16x8 wf[4];
        #pragma unroll
        for (int s = 0; s < 4; ++s) wf[s] = *(const bf16x8*)&pb[s * 512];
        f32x4 acc[2] = {{0.f,0.f,0.f,0.f},{0.f,0.f,0.f,0.f}};
        #pragma unroll
        for (int mt = 0; mt < 2; ++mt)
            #pragma unroll
            for (int s = 0; s < 4; ++s)
                acc[mt] = __builtin_amdgcn_mfma_f32_16x16x32_bf16(xf[mt][s], wf[s], acc[mt], 0, 0, 0);
        #pragma unroll
        for (int mt = 0; mt < 2; ++mt) {
            int addr = (ntv * 16 + lrow) * 40 + mt * 16 + quad * 4;
            uint2 pk; pk.x = pack2(acc[mt][0], acc[mt][1]); pk.y = pack2(acc[mt][2], acc[mt][3]);
            *(uint2*)&vT_s[addr] = pk;
        }
    }
    __syncthreads();

    // ---- phase 2: S_h = T_h X^T (scale already in M) -> s_s[64][36] ----
    #pragma unroll
    for (int tt = 0; tt < 2; ++tt) {
        int ti = wave * 2 + tt;               // 0..7 = h(2) x it(2) x jt(2)
        int h = ti >> 2, it = (ti >> 1) & 1, jt = ti & 1;
        f32x4 acc = {0.f, 0.f, 0.f, 0.f};
        #pragma unroll
        for (int s = 0; s < 4; ++s) {
            bf16x8 at = *(const bf16x8*)&t_s[(it * 16 + lrow) * 264 + h * 128 + s * 32 + quad * 8];
            acc = __builtin_amdgcn_mfma_f32_16x16x32_bf16(at, xf[jt][s], acc, 0, 0, 0);
        }
        #pragma unroll
        for (int r = 0; r < 4; ++r)
            s_s[(h * 32 + it * 16 + quad * 4 + r) * 36 + jt * 16 + lrow] = acc[r];
    }
    __syncthreads();

    // ---- phase 3: sparsemax, tau = max_k (cumsum_k - 1)/k ----
    // Lane (hh=lane>>5, j=lane&31) handles column j of row (hh*32 + i).
    // Each lane loads the full row (broadcast b128 reads), computes its own
    // rank and strict-greater prefix sum locally (32 independent cmp/adds),
    // then a single 5-step shuffle max. Ties: strict compare (prob ~0 fp32).
    {
        int j  = lane & 31;
        int hh = lane >> 5;
        #pragma unroll
        for (int ii = 0; ii < 8; ++ii) {
            int i   = wave * 8 + ii;
            int row = hh * 32 + i;
            const float* zr = &s_s[row * 36];
            float z[32];
            #pragma unroll
            for (int c = 0; c < 8; ++c) {
                float4 f = *(const float4*)&zr[c * 4];
                z[c*4] = f.x; z[c*4+1] = f.y; z[c*4+2] = f.z; z[c*4+3] = f.w;
            }
            float zj = zr[j];
            float c0 = 0.f, c1 = 0.f, s0 = 0.f, s1 = 0.f;
            #pragma unroll
            for (int l = 0; l < 32; l += 2) {
                bool g0 = z[l]     > zj;
                bool g1 = z[l + 1] > zj;
                c0 += g0 ? 1.f : 0.f;  s0 += g0 ? z[l]     : 0.f;
                c1 += g1 ? 1.f : 0.f;  s1 += g1 ? z[l + 1] : 0.f;
            }
            float rk  = c0 + c1 + 1.f;            // this lane's rank k
            float cum = s0 + s1 + zj;             // cumsum of top-k
            float tc  = (cum - 1.f) / rk;         // tau_k
            #pragma unroll
            for (int m = 1; m <= 16; m <<= 1) tc = fmaxf(tc, __shfl_xor(tc, m, 32));
            float w = fmaxf(zj - tc, 0.f);
            ((short*)zr)[j] = f2bf(w);            // w row aliases S row start
            float wo = __shfl_xor(w, 32);         // pair heads for coalesced store
            if (lane < 32) {
                float2 v; v.x = w; v.y = wo;
                *(float2*)&wgt[((size_t)b * 32 + i) * 64 + j * 2] = v;
            }
        }
    }
    __syncthreads();

    // ---- phase 4: out = 0.5*(W_0 V_0 + W_1 V_1) ----
    #pragma unroll
    for (int tt = 0; tt < 4; ++tt) {
        int ti = wave * 4 + tt;               // 0..15 = it(2) x dt(8)
        int it = ti >> 3, dt = ti & 7;
        f32x4 acc = {0.f, 0.f, 0.f, 0.f};
        #pragma unroll
        for (int h = 0; h < 2; ++h) {
            bf16x8 aw = *(const bf16x8*)((short*)&s_s[(h * 32 + it * 16 + lrow) * 36] + quad * 8);
            bf16x8 bv = *(const bf16x8*)&vT_s[(h * 128 + dt * 16 + lrow) * 40 + quad * 8];
            acc = __builtin_amdgcn_mfma_f32_16x16x32_bf16(aw, bv, acc, 0, 0, 0);
        }
        #pragma unroll
        for (int r = 0; r < 4; ++r)
            out[((size_t)b * 32 + it * 16 + quad * 4 + r) * 128 + dt * 16 + lrow] = acc[r] * 0.5f;
    }
}

extern "C" void kernel_launch(void* const* d_in, const int* in_sizes, int n_in,
                              void* d_out, int out_size, void* d_ws, size_t ws_size,
                              hipStream_t stream) {
    const float* x  = (const float*)d_in[0];  // [4096,32,128] fp32
    const float* WK = (const float*)d_in[1];  // [128,256] fp32
    const float* WV = (const float*)d_in[2];
    const float* WQ = (const float*)d_in[3];
    float* out = (float*)d_out;               // [131072,128] fp32
    float* wgt = out + (size_t)NG * 32 * 128; // [131072,32,2] fp32
    short* pm = (short*)d_ws;                 // 32768 bf16 = 65536 B
    short* pv = pm + 32768;                   // 32768 bf16 = 65536 B

    hipLaunchKernelGGL(pack_m_kernel, dim3(128), dim3(256), 0, stream, WQ, WK, pm);
    hipLaunchKernelGGL(pack_v_kernel, dim3(128), dim3(256), 0, stream, WV, pv);
    hipLaunchKernelGGL(fused_attn_kernel, dim3(NG), dim3(256), 0, stream, x, pm, pv, out, wgt);
}